// Round 1
// 320.494 us; speedup vs baseline: 1.0156x; 1.0156x over previous
//
#include <hip/hip_runtime.h>

// sample_pdf (NeRF hierarchical sampling), fp32.
// bins: [N, 64] sorted edges; weights: [N, 63]; u: [N, 128] -> out [N, 128].
//
// One wave64 per ray; 4 rays per 256-thread block.
// R1: LDS-pipe bound. R2: DPP scan + 3 reg levels + lo-tracking (325 us).
// R3 (this): VALU + dependent-chain attack.
//   - exclusive-scan cdf layout: lane l holds cdf[l]  -> single ds_write,
//     and ALL gathers (lo/chi/blo/bhi) become conflict-free ds_bpermute
//     on register-held values (one parallel lgkm round).
//   - flat level-A search: grp = popcount-style sum of 7 SGPR-pivot compares.
//   - pos is 8-aligned -> remaining 8 cdf entries via 2 independent
//     ds_read_b128 (replaces 3 *dependent* divergent ds_read_b32).
//   - precise fp32 div (~10 VALU each) -> v_rcp_f32 + mul; cdf[63] forced to
//     exactly 1.0f so uv<1 guarantees upper<=63.

constexpr int NBINS = 64;
constexpr int NW = NBINS - 1;
constexpr int NIMP = 128;
constexpr int RAYS_PER_BLOCK = 4;

template <int Ctrl, int Rm>
__device__ __forceinline__ float dppterm(float x) {
    // update_dpp(old=0,...): lanes with invalid source (bound_ctrl) or masked-off
    // rows (row_mask) produce 0, so "x += dppterm(x)" is the identity there.
    return __int_as_float(__builtin_amdgcn_update_dpp(
        0, __float_as_int(x), Ctrl, Rm, 0xF, true));
}

__device__ __forceinline__ float rdlane(float x, int lane) {
    return __int_as_float(__builtin_amdgcn_readlane(__float_as_int(x), lane));
}

// pull: result = src@lane[idx] (full wave64 crossbar, no LDS storage, no conflicts)
__device__ __forceinline__ float bperm_f(float x, int lane_idx) {
    return __int_as_float(
        __builtin_amdgcn_ds_bpermute(lane_idx << 2, __float_as_int(x)));
}

// wave64 inclusive scan, pure VALU (DPP), no DS ops
__device__ __forceinline__ float wave_incl_scan(float x) {
    x += dppterm<0x111, 0xF>(x);  // row_shr:1
    x += dppterm<0x112, 0xF>(x);  // row_shr:2
    x += dppterm<0x114, 0xF>(x);  // row_shr:4
    x += dppterm<0x118, 0xF>(x);  // row_shr:8  -> per-16 row scans
    x += dppterm<0x142, 0xA>(x);  // row_bcast:15 -> rows 1,3 get row 0/2 totals
    x += dppterm<0x143, 0xC>(x);  // row_bcast:31 -> lanes 32..63 get total(0..31)
    return x;
}

__global__ __launch_bounds__(256) void sample_pdf_kernel(
    const float* __restrict__ bins,
    const float* __restrict__ weights,
    const float* __restrict__ u,
    float* __restrict__ out,
    int n_rays)
{
    __shared__ alignas(16) float s_cdf[RAYS_PER_BLOCK][NBINS];  // 1 KiB

    const int wave = threadIdx.x >> 6;
    const int lane = threadIdx.x & 63;
    int ray = blockIdx.x * RAYS_PER_BLOCK + wave;
    if (ray >= n_rays) ray = n_rays - 1;  // tail: duplicated work, identical writes
    const uint32_t rb = (uint32_t)ray;    // 32-bit offsets: all arrays < 4 GiB

    // issue all three global loads up front (independent)
    const float bv = bins[rb * NBINS + lane];
    const float w = (lane < NW) ? (weights[rb * NW + lane] + 1e-5f) : 0.0f;
    const float2 uu = ((const float2*)u)[rb * (NIMP / 2) + lane];

    // weights scan -> EXCLUSIVE normalized cdf: lane l holds cdf[l]
    const float S = wave_incl_scan(w);
    const float T = rdlane(S, 63);                 // total (w@63 = 0)
    const float rcpT = __builtin_amdgcn_rcpf(T);   // approx ok: tolerance loose
    float cdfv = (S - w) * rcpT;                   // cdf[lane]; lane0 -> 0.0 exactly
    if (lane == NBINS - 1) cdfv = 1.0f;            // exact top: cdf[63]=1 > any u<1

    s_cdf[wave][lane] = cdfv;  // single unpredicated ds_write; wave-private row,
                               // same-wave ordering via compiler lgkmcnt (no barrier)

    // level-A pivots cdf[8k] as wave-uniform scalars (SGPRs)
    const float c8  = rdlane(cdfv, 8);
    const float c16 = rdlane(cdfv, 16);
    const float c24 = rdlane(cdfv, 24);
    const float c32 = rdlane(cdfv, 32);
    const float c40 = rdlane(cdfv, 40);
    const float c48 = rdlane(cdfv, 48);
    const float c56 = rdlane(cdfv, 56);

    const float* cdf = s_cdf[wave];
    float2 res;

    #pragma unroll
    for (int k = 0; k < 2; ++k) {
        const float uv = (k == 0) ? uu.x : uu.y;

        // ---- level A: which 8-aligned group (flat, no mux tree) ----
        // pivots sorted => (pivot < uv) is monotone => grp = sum of flags
        const int grp = (int)(c8 < uv) + (int)(c16 < uv) + (int)(c24 < uv) +
                        (int)(c32 < uv) + (int)(c40 < uv) + (int)(c48 < uv) +
                        (int)(c56 < uv);
        const int pos = grp << 3;  // multiple of 8 -> 32B-aligned LDS offset

        // ---- level B: 8-entry range in ONE lgkm round (2 independent b128) ----
        const float4 g0 = *(const float4*)(cdf + pos);
        const float4 g1 = *(const float4*)(cdf + pos + 4);

        const int cnt = (int)(g0.y < uv) + (int)(g0.z < uv) + (int)(g0.w < uv) +
                        (int)(g1.x < uv) + (int)(g1.y < uv) + (int)(g1.z < uv) +
                        (int)(g1.w < uv);

        // lower = largest i with cdf[i] < uv (0 if none); uv<1 & cdf[63]=1
        // guarantee lower<=62, so upper<=63. uv<=0 -> upper=0 -> chi=cdf[0]=0
        // falls out of the bpermute with no special case.
        const int lower = pos + cnt;
        const int upper = (uv > 0.0f) ? (lower + 1) : 0;

        // ---- all 4 gathers: one parallel round of conflict-free bpermutes ----
        const float lo  = bperm_f(cdfv, lower);
        const float chi = bperm_f(cdfv, upper);
        const float blo = bperm_f(bv, lower);
        const float bhi = bperm_f(bv, upper);

        float denom = chi - lo;
        denom = (denom < 1e-5f) ? 1.0f : denom;
        const float t = (uv - lo) * __builtin_amdgcn_rcpf(denom);
        const float sm = __builtin_fmaf(t, bhi - blo, blo);
        if (k == 0) res.x = sm;
        else        res.y = sm;
    }

    ((float2*)out)[rb * (NIMP / 2) + lane] = res;
}

extern "C" void kernel_launch(void* const* d_in, const int* in_sizes, int n_in,
                              void* d_out, int out_size, void* d_ws, size_t ws_size,
                              hipStream_t stream) {
    const float* bins    = (const float*)d_in[0];
    const float* weights = (const float*)d_in[1];
    const float* u       = (const float*)d_in[2];
    float* out = (float*)d_out;

    const int n_rays = in_sizes[0] / NBINS;
    const int grid = (n_rays + RAYS_PER_BLOCK - 1) / RAYS_PER_BLOCK;
    sample_pdf_kernel<<<grid, 256, 0, stream>>>(bins, weights, u, out, n_rays);
}

// Round 2
// 304.041 us; speedup vs baseline: 1.0706x; 1.0541x over previous
//
#include <hip/hip_runtime.h>

// sample_pdf (NeRF hierarchical sampling), fp32.
// bins: [N, 64] sorted edges; weights: [N, 63]; u: [N, 128] -> out [N, 128].
//
// R1: LDS-pipe bound. R2: DPP scan + 3 reg levels (325 us).
// R3: bpermute gathers + flat level-A + rcp: VALU 57->41% but dur ~flat
//     -> latency-bound, no pipe saturated.
// R4 (this): 2 rays per wave, everything duplicated & interleaved.
//     6 independent global loads up front, 2 independent scans,
//     4 independent sample chains per wave (was 2). Pure ILP play:
//     same instruction count per ray, ~2x issue-eligible work per slot.

constexpr int NBINS = 64;
constexpr int NW = NBINS - 1;
constexpr int NIMP = 128;
constexpr int WAVES_PER_BLOCK = 4;
constexpr int RAYS_PER_WAVE = 2;
constexpr int RAYS_PER_BLOCK = WAVES_PER_BLOCK * RAYS_PER_WAVE;  // 8

template <int Ctrl, int Rm>
__device__ __forceinline__ float dppterm(float x) {
    // update_dpp(old=0,...): lanes with invalid source (bound_ctrl) or masked-off
    // rows (row_mask) produce 0, so "x += dppterm(x)" is the identity there.
    return __int_as_float(__builtin_amdgcn_update_dpp(
        0, __float_as_int(x), Ctrl, Rm, 0xF, true));
}

__device__ __forceinline__ float rdlane(float x, int lane) {
    return __int_as_float(__builtin_amdgcn_readlane(__float_as_int(x), lane));
}

// pull: result = src@lane[idx] (full wave64 crossbar on register values)
__device__ __forceinline__ float bperm_f(float x, int lane_idx) {
    return __int_as_float(
        __builtin_amdgcn_ds_bpermute(lane_idx << 2, __float_as_int(x)));
}

// wave64 inclusive scan, pure VALU (DPP), no DS ops
__device__ __forceinline__ float wave_incl_scan(float x) {
    x += dppterm<0x111, 0xF>(x);  // row_shr:1
    x += dppterm<0x112, 0xF>(x);  // row_shr:2
    x += dppterm<0x114, 0xF>(x);  // row_shr:4
    x += dppterm<0x118, 0xF>(x);  // row_shr:8  -> per-16 row scans
    x += dppterm<0x142, 0xA>(x);  // row_bcast:15 -> rows 1,3 get row 0/2 totals
    x += dppterm<0x143, 0xC>(x);  // row_bcast:31 -> lanes 32..63 get total(0..31)
    return x;
}

struct Pivots { float c8, c16, c24, c32, c40, c48, c56; };

__device__ __forceinline__ Pivots make_pivots(float cdfv) {
    Pivots p;
    p.c8  = rdlane(cdfv, 8);
    p.c16 = rdlane(cdfv, 16);
    p.c24 = rdlane(cdfv, 24);
    p.c32 = rdlane(cdfv, 32);
    p.c40 = rdlane(cdfv, 40);
    p.c48 = rdlane(cdfv, 48);
    p.c56 = rdlane(cdfv, 56);
    return p;
}

__device__ __forceinline__ float sample_one(float uv, const float* cdf,
                                            float cdfv, float bv,
                                            const Pivots& P)
{
    // level A: which 8-aligned group (pivots sorted => flags monotone => sum)
    const int grp = (int)(P.c8 < uv) + (int)(P.c16 < uv) + (int)(P.c24 < uv) +
                    (int)(P.c32 < uv) + (int)(P.c40 < uv) + (int)(P.c48 < uv) +
                    (int)(P.c56 < uv);
    const int pos = grp << 3;  // 32B-aligned LDS offset

    // level B: 8-entry range in one lgkm round (2 independent b128)
    const float4 g0 = *(const float4*)(cdf + pos);
    const float4 g1 = *(const float4*)(cdf + pos + 4);
    const int cnt = (int)(g0.y < uv) + (int)(g0.z < uv) + (int)(g0.w < uv) +
                    (int)(g1.x < uv) + (int)(g1.y < uv) + (int)(g1.z < uv) +
                    (int)(g1.w < uv);

    // lower = largest i with cdf[i] < uv (0 if none); cdf[63]=1 exact keeps
    // lower<=62 for uv<1. uv<=0 -> upper=0 -> chi=cdf[0]=0 falls out free.
    const int lower = pos + cnt;
    const int upper = (uv > 0.0f) ? (lower + 1) : 0;

    // all 4 gathers in one parallel crossbar round
    const float lo  = bperm_f(cdfv, lower);
    const float chi = bperm_f(cdfv, upper);
    const float blo = bperm_f(bv, lower);
    const float bhi = bperm_f(bv, upper);

    float denom = chi - lo;
    denom = (denom < 1e-5f) ? 1.0f : denom;
    const float t = (uv - lo) * __builtin_amdgcn_rcpf(denom);
    return __builtin_fmaf(t, bhi - blo, blo);
}

__global__ __launch_bounds__(256) void sample_pdf_kernel(
    const float* __restrict__ bins,
    const float* __restrict__ weights,
    const float* __restrict__ u,
    float* __restrict__ out,
    int n_rays)
{
    __shared__ alignas(16) float s_cdf[WAVES_PER_BLOCK][RAYS_PER_WAVE][NBINS];

    const int wave = threadIdx.x >> 6;
    const int lane = threadIdx.x & 63;
    const int base = blockIdx.x * RAYS_PER_BLOCK + wave * RAYS_PER_WAVE;
    // tail: clamped rays recompute ray n-1; identical values, benign dup writes
    const uint32_t rA = (uint32_t)min(base,     n_rays - 1);
    const uint32_t rB = (uint32_t)min(base + 1, n_rays - 1);

    // 6 independent global loads issued up front
    const float bvA = bins[rA * NBINS + lane];
    const float bvB = bins[rB * NBINS + lane];
    const float wA = (lane < NW) ? (weights[rA * NW + lane] + 1e-5f) : 0.0f;
    const float wB = (lane < NW) ? (weights[rB * NW + lane] + 1e-5f) : 0.0f;
    const float2 uuA = ((const float2*)u)[rA * (NIMP / 2) + lane];
    const float2 uuB = ((const float2*)u)[rB * (NIMP / 2) + lane];

    // two independent DPP scan chains -> exclusive normalized cdfs
    const float SA = wave_incl_scan(wA);
    const float SB = wave_incl_scan(wB);
    float cdfvA = (SA - wA) * __builtin_amdgcn_rcpf(rdlane(SA, 63));
    float cdfvB = (SB - wB) * __builtin_amdgcn_rcpf(rdlane(SB, 63));
    if (lane == NBINS - 1) { cdfvA = 1.0f; cdfvB = 1.0f; }  // exact top

    // wave-private LDS rows; same-wave write->read order via compiler lgkmcnt
    s_cdf[wave][0][lane] = cdfvA;
    s_cdf[wave][1][lane] = cdfvB;

    const Pivots PA = make_pivots(cdfvA);
    const Pivots PB = make_pivots(cdfvB);

    const float* cA = s_cdf[wave][0];
    const float* cB = s_cdf[wave][1];

    // 4 independent sample chains
    float2 resA, resB;
    resA.x = sample_one(uuA.x, cA, cdfvA, bvA, PA);
    resA.y = sample_one(uuA.y, cA, cdfvA, bvA, PA);
    resB.x = sample_one(uuB.x, cB, cdfvB, bvB, PB);
    resB.y = sample_one(uuB.y, cB, cdfvB, bvB, PB);

    ((float2*)out)[rA * (NIMP / 2) + lane] = resA;
    ((float2*)out)[rB * (NIMP / 2) + lane] = resB;
}

extern "C" void kernel_launch(void* const* d_in, const int* in_sizes, int n_in,
                              void* d_out, int out_size, void* d_ws, size_t ws_size,
                              hipStream_t stream) {
    const float* bins    = (const float*)d_in[0];
    const float* weights = (const float*)d_in[1];
    const float* u       = (const float*)d_in[2];
    float* out = (float*)d_out;

    const int n_rays = in_sizes[0] / NBINS;
    const int grid = (n_rays + RAYS_PER_BLOCK - 1) / RAYS_PER_BLOCK;
    sample_pdf_kernel<<<grid, 256, 0, stream>>>(bins, weights, u, out, n_rays);
}